// Round 1
// baseline (139.671 us; speedup 1.0000x reference)
//
#include <hip/hip_runtime.h>
#include <cmath>

// ---------------------------------------------------------------------------
// Problem constants (from reference)
// ---------------------------------------------------------------------------
constexpr int kNsh    = 9;      // (LMAX+1)^2, LMAX=2
constexpr int kF      = 64;
constexpr int kNrbf   = 20;
constexpr int kNAtoms = 1000;
constexpr int kNPairs = 10000;
constexpr float kCutoffF = 5.0f;
constexpr int kMaxNZ  = 200;
constexpr int kCp     = 12;         // channel dim padded (9 -> 12) for b128
constexpr int kXs     = kF * kCp;   // 768 floats per atom, internal layout

// ---------------------------------------------------------------------------
// Compile-time real Clebsch-Gordan table (mirrors the reference _real_cg)
// ---------------------------------------------------------------------------
struct CGSparse {
  int n;
  int c[kMaxNZ];
  int a[kMaxNZ];
  int b[kMaxNZ];
  float v[kMaxNZ];
};

constexpr double cfact(int n) {
  double r = 1.0;
  for (int i = 2; i <= n; i++) r *= (double)i;
  return r;
}
constexpr double cabs_(double x) { return x < 0 ? -x : x; }
constexpr double csqrt_(double x) {
  if (x <= 0.0) return 0.0;
  double g = x < 1.0 ? 1.0 : x;
  for (int i = 0; i < 60; i++) g = 0.5 * (g + x / g);
  return g;
}

constexpr double cg_cplx(int l1, int m1, int l2, int m2, int l3, int m3) {
  if (m3 != m1 + m2) return 0.0;
  int lo = l1 > l2 ? l1 - l2 : l2 - l1;
  if (l3 < lo || l3 > l1 + l2) return 0.0;
  double pre = csqrt_((2 * l3 + 1) * cfact(l3 + l1 - l2) * cfact(l3 - l1 + l2) *
                      cfact(l1 + l2 - l3) / cfact(l1 + l2 + l3 + 1));
  pre *= csqrt_(cfact(l3 + m3) * cfact(l3 - m3) * cfact(l1 - m1) *
                cfact(l1 + m1) * cfact(l2 - m2) * cfact(l2 + m2));
  double s = 0.0;
  for (int k = 0; k <= l1 + l2 - l3; k++) {
    int d0 = k, d1 = l1 + l2 - l3 - k, d2 = l1 - m1 - k;
    int d3 = l2 + m2 - k, d4 = l3 - l2 + m1 + k, d5 = l3 - l1 - m2 + k;
    if (d0 < 0 || d1 < 0 || d2 < 0 || d3 < 0 || d4 < 0 || d5 < 0) continue;
    double den = cfact(d0) * cfact(d1) * cfact(d2) * cfact(d3) * cfact(d4) * cfact(d5);
    s += ((k % 2) ? -1.0 : 1.0) / den;
  }
  return pre * s;
}

constexpr CGSparse build_cg() {
  CGSparse out{};
  int lidx[9] = {0, 1, 1, 1, 2, 2, 2, 2, 2};
  int midx[9] = {0, -1, 0, 1, -2, -1, 0, 1, 2};
  double Ur[9][9] = {};
  double Ui[9][9] = {};
  for (int l = 0; l <= 2; l++) {
    int base = l * l + l;
    Ur[base][base] = 1.0;
    for (int m = 1; m <= l; m++) {
      double s2 = 1.0 / csqrt_(2.0);
      double sgn = (m % 2) ? -1.0 : 1.0;
      Ur[base + m][base - m] = s2;
      Ur[base + m][base + m] = sgn * s2;
      Ui[base - m][base - m] = s2;
      Ui[base - m][base + m] = -sgn * s2;
    }
  }
  double cgr[9][9][9] = {};
  for (int i = 0; i < 9; i++)
    for (int j = 0; j < 9; j++)
      for (int k = 0; k < 9; k++) {
        double cv = cg_cplx(lidx[i], midx[i], lidx[j], midx[j], lidx[k], midx[k]);
        if (cv == 0.0) continue;
        for (int a2 = 0; a2 < 9; a2++) {
          if (Ur[a2][i] == 0.0 && Ui[a2][i] == 0.0) continue;
          for (int b2 = 0; b2 < 9; b2++) {
            if (Ur[b2][j] == 0.0 && Ui[b2][j] == 0.0) continue;
            for (int c2 = 0; c2 < 9; c2++) {
              if (Ur[c2][k] == 0.0 && Ui[c2][k] == 0.0) continue;
              double ar = Ur[a2][i], ai = Ui[a2][i];
              double br = Ur[b2][j], bi = Ui[b2][j];
              double cr = Ur[c2][k], ci = -Ui[c2][k];  // conj
              double pr = ar * br - ai * bi;
              double pi = ar * bi + ai * br;
              double rr = pr * cr - pi * ci;  // real part
              cgr[c2][a2][b2] += rr * cv;
            }
          }
        }
      }
  int n = 0;
  for (int c2 = 0; c2 < 9; c2++)
    for (int a2 = 0; a2 < 9; a2++)
      for (int b2 = 0; b2 < 9; b2++) {
        bool mask = ((lidx[a2] + lidx[b2]) % 2) == (lidx[c2] % 2);
        double v = mask ? cgr[c2][a2][b2] : 0.0;
        if (cabs_(v) > 1e-9) {
          out.c[n] = c2;
          out.a[n] = a2;
          out.b[n] = b2;
          out.v[n] = (float)v;
          n++;
        }
      }
  out.n = n;
  return out;
}

constexpr CGSparse CG = build_cg();
static_assert(CG.n > 0 && CG.n <= kMaxNZ, "CG table size out of range");

// ---------------------------------------------------------------------------
// k_pre: three block families in one dispatch.
//  [0, 2500)        per-pair record pd[32]: Y[0..8], cut[9], radial*cut[10..29]
//  [2500, 2504)     segment offsets (binary search over sorted idx_i)
//  [2504, 3004)     per-pair filters pairW[t][p][192]:
//                   W = bf*cut + sum_k (radial_k*cut) * Wf[k][:]
//                   (Wf cached in 60 VGPRs per wave; radial recomputed from
//                    r_ij so there is no intra-dispatch dependency on pd)
// ---------------------------------------------------------------------------
constexpr int kPreBlkPairs = kNPairs / 4;                 // 2500
constexpr int kPreBlkSeg   = (kNAtoms + 1 + 255) / 256;   // 4
constexpr int kFiltPPW     = 10;                          // pairs per wave
constexpr int kFiltWaves   = 2 * kNPairs / kFiltPPW;      // 2000
constexpr int kFiltBlocks  = kFiltWaves / 4;              // 500
constexpr int kPreBlkTotal = kPreBlkPairs + kPreBlkSeg + kFiltBlocks;

__global__ __launch_bounds__(256) void k_pre(
    const float* __restrict__ rij, const int* __restrict__ idx_i,
    const float* __restrict__ Wf, const float* __restrict__ bf,
    float* __restrict__ pd_all, float* __restrict__ pairW,
    int* __restrict__ seg) {
  const int blk = blockIdx.x;
  if (blk < kPreBlkPairs) {
    int wv = threadIdx.x >> 6;
    int f = threadIdx.x & 63;
    int p = blk * 4 + wv;
    float rx = rij[3 * p + 0], ry = rij[3 * p + 1], rz = rij[3 * p + 2];
    float d = sqrtf(rx * rx + ry * ry + rz * rz);
    float inv = 1.0f / d;
    float x = rx * inv, y = ry * inv, z = rz * inv;
    const float c0 = 0.28209479177387814f;  // 0.5/sqrt(pi)
    const float c1 = 0.4886025119029199f;   // sqrt(3/(4pi))
    const float c2 = 1.0925484305920792f;   // 0.5*sqrt(15/pi)
    const float c3 = 0.31539156525252005f;  // 0.25*sqrt(5/pi)
    const float c4 = 0.5462742152960396f;   // 0.25*sqrt(15/pi)
    float cut = (d < kCutoffF) ? 0.5f * (cosf(d * (float)(M_PI / 5.0)) + 1.0f) : 0.0f;
    float val = 0.f;
    if (f < 9) {
      val =
          (f == 0) ? c0 :
          (f == 1) ? c1 * y :
          (f == 2) ? c1 * z :
          (f == 3) ? c1 * x :
          (f == 4) ? c2 * x * y :
          (f == 5) ? c2 * y * z :
          (f == 6) ? c3 * (3.0f * z * z - 1.0f) :
          (f == 7) ? c2 * x * z :
                     c4 * (x * x - y * y);
    } else if (f == 9) {
      val = cut;
    } else if (f < 30) {
      const float width = kCutoffF / (kNrbf - 1);
      const float coef = -0.5f / (width * width);
      float off = (kCutoffF * (f - 10)) / (kNrbf - 1);
      float tt = d - off;
      val = expf(coef * tt * tt) * cut;   // radial*cut (bias term uses cut)
    }
    if (f < 30) pd_all[p * 32 + f] = val;
  } else if (blk < kPreBlkPairs + kPreBlkSeg) {
    int a = (blk - kPreBlkPairs) * 256 + threadIdx.x;
    if (a <= kNAtoms) {
      int lo = 0, hi = kNPairs;
      while (lo < hi) {
        int mid = (lo + hi) >> 1;
        if (idx_i[mid] < a) lo = mid + 1; else hi = mid;
      }
      seg[a] = lo;
    }
  } else {
    // ---- filter blocks: pairW[t][p][192] ----
    const int wid = (blk - kPreBlkPairs - kPreBlkSeg) * 4 + (threadIdx.x >> 6);
    const int lane = threadIdx.x & 63;
    const int t = wid / (kFiltWaves / 2);
    const int chunk = wid % (kFiltWaves / 2);
    const float* Wft = Wf + t * kNrbf * 192;
    float w0r[kNrbf], w1r[kNrbf], w2r[kNrbf];
    #pragma unroll
    for (int k = 0; k < kNrbf; k++) {
      w0r[k] = Wft[k * 192 + lane];
      w1r[k] = Wft[k * 192 + 64 + lane];
      w2r[k] = Wft[k * 192 + 128 + lane];
    }
    const float b0 = bf[t * 192 + lane];
    const float b1 = bf[t * 192 + 64 + lane];
    const float b2 = bf[t * 192 + 128 + lane];
    float* outt = pairW + t * kNPairs * 192;
    const float width = kCutoffF / (kNrbf - 1);
    const float coef = -0.5f / (width * width);
    for (int i = 0; i < kFiltPPW; i++) {
      const int p = __builtin_amdgcn_readfirstlane(chunk * kFiltPPW + i);
      float rx = rij[3 * p + 0], ry = rij[3 * p + 1], rz = rij[3 * p + 2];
      float d = sqrtf(rx * rx + ry * ry + rz * rz);
      float cut = (d < kCutoffF) ? 0.5f * (cosf(d * (float)(M_PI / 5.0)) + 1.0f) : 0.0f;
      float a0 = b0 * cut, a1 = b1 * cut, a2 = b2 * cut;
      #pragma unroll
      for (int k = 0; k < kNrbf; k++) {
        float off = (kCutoffF * k) / (kNrbf - 1);
        float tt = d - off;
        float r = expf(coef * tt * tt) * cut;
        a0 += r * w0r[k];
        a1 += r * w1r[k];
        a2 += r * w2r[k];
      }
      outt[p * 192 + lane] = a0;
      outt[p * 192 + 64 + lane] = a1;
      outt[p * 192 + 128 + lane] = a2;
    }
  }
}

// ---------------------------------------------------------------------------
// Helpers
// ---------------------------------------------------------------------------
// k-split matmul partial: wave covers 16 k-slices of the 12c x 64f tile.
// W streamed from global (L2-broadcast) in two 8-slice register stages.
__device__ __forceinline__ void mm_phase(const float* __restrict__ sIn,
                                         const float* __restrict__ W,
                                         float* __restrict__ sRw,
                                         int k0, int cgi, int fb) {
  if (cgi >= 3) return;
  const int c0 = cgi * 4;
  float acc[4][4];
  #pragma unroll
  for (int i = 0; i < 4; i++)
    #pragma unroll
    for (int j = 0; j < 4; j++) acc[i][j] = 0.f;
  #pragma unroll
  for (int half = 0; half < 2; half++) {
    float4 wr[8];
    #pragma unroll
    for (int kk = 0; kk < 8; kk++) {
      wr[kk] = *(const float4*)(W + (k0 + half * 8 + kk) * kF + fb);
    }
    #pragma unroll
    for (int kk = 0; kk < 8; kk++) {
      int k = k0 + half * 8 + kk;
      float4 av = *(const float4*)(sIn + k * kCp + c0);
      float4 wv = wr[kk];
      float a[4] = {av.x, av.y, av.z, av.w};
      float w[4] = {wv.x, wv.y, wv.z, wv.w};
      #pragma unroll
      for (int i = 0; i < 4; i++)
        #pragma unroll
        for (int j = 0; j < 4; j++) acc[i][j] += a[i] * w[j];
    }
  }
  #pragma unroll
  for (int j = 0; j < 4; j++) {
    float4 v = {acc[0][j], acc[1][j], acc[2][j], acc[3][j]};
    *(float4*)(sRw + (fb + j) * kCp + c0) = v;
  }
}

// ---------------------------------------------------------------------------
// k_inter<T>: fused message + update, one block (4 waves) per atom.
// Filters are PRECOMPUTED per pair in pairW (no sWf staging, no per-pair
// radial reconstruction) -> 3 coalesced global loads per pair.
// T==0: gather emb[Z[j]] (x0 virtual), write internal [f][12].
// T==1: gather x1, write standard [c][f] to out.
// ---------------------------------------------------------------------------
template <int T>
__global__ __launch_bounds__(256) void k_inter(
    const float* __restrict__ pd_all, const float* __restrict__ pairW,
    const int* __restrict__ seg, const int* __restrict__ idx_j,
    const int* __restrict__ Z, const float* __restrict__ emb,
    const float* __restrict__ x_in,
    const float* __restrict__ W1, const float* __restrict__ W2,
    const float* __restrict__ W3, const float* __restrict__ Wg,
    const float* __restrict__ bg, float* __restrict__ x_out) {
  const int atom = blockIdx.x;
  const int tid = threadIdx.x;
  const int wv = tid >> 6;          // wave 0..3
  const int lane = tid & 63;
  const int cgi = lane >> 4;        // 0..3 (3 idle in mm)
  const int fb = (lane & 15) * 4;
  const int k0 = wv * 16;           // k-range for this wave

  __shared__ __align__(16) float sA[kF * kCp];      // 3 KB staging, f-major
  __shared__ __align__(16) float sR[4][kF * kCp];   // 12 KB per-wave partials
  __shared__ __align__(16) float sGp[4][192];       // 3 KB gate partials

  // ---- message + aggregation (pairs split across 4 waves) ----
  {
    float y[12];
    #pragma unroll
    for (int c = 0; c < 12; c++) y[c] = 0.f;
    const int s0 = seg[atom], s1 = seg[atom + 1];
    for (int p0 = s0 + wv; p0 < s1; p0 += 4) {
      const int p = __builtin_amdgcn_readfirstlane(p0);
      const int j = __builtin_amdgcn_readfirstlane(idx_j[p]);
      const float* pd = pd_all + p * 32;
      const float* wp = pairW + p * 192;
      float Wl0 = wp[lane];
      float Wl1 = wp[64 + lane];
      float Wl2 = wp[128 + lane];
      float YW[9];
      YW[0] = pd[0] * Wl0;
      YW[1] = pd[1] * Wl1;
      YW[2] = pd[2] * Wl1;
      YW[3] = pd[3] * Wl1;
      #pragma unroll
      for (int b = 4; b < 9; b++) YW[b] = pd[b] * Wl2;
      if (T == 0) {
        // x[j] = emb[Z[j]] in channel 0 only: CG folds to a==0 entries
        float e = emb[Z[j] * kF + lane];
        #pragma unroll
        for (int q = 0; q < CG.n; q++) {
          if (CG.a[q] == 0) y[CG.c[q]] += CG.v[q] * YW[CG.b[q]] * e;
        }
      } else {
        const float* xj = x_in + j * kXs + lane * kCp;
        float xv[12];
        *(float4*)&xv[0] = *(const float4*)(xj + 0);
        *(float4*)&xv[4] = *(const float4*)(xj + 4);
        *(float4*)&xv[8] = *(const float4*)(xj + 8);
        #pragma unroll
        for (int q = 0; q < CG.n; q++) {
          y[CG.c[q]] += CG.v[q] * YW[CG.b[q]] * xv[CG.a[q]];
        }
      }
    }
    float4* r4 = (float4*)(sR[wv] + lane * kCp);
    r4[0] = *(float4*)&y[0];
    r4[1] = *(float4*)&y[4];
    r4[2] = *(float4*)&y[8];
  }
  __syncthreads();  // B1
  // reduce partials -> sA (dx, f-major); float4 granularity
  if (tid < 192) {
    const float4* r0 = (const float4*)sR[0];
    const float4* r1 = (const float4*)sR[1];
    const float4* r2 = (const float4*)sR[2];
    const float4* r3 = (const float4*)sR[3];
    float4 a = r0[tid], b = r1[tid], c = r2[tid], d = r3[tid];
    float4 s = {a.x + b.x + c.x + d.x, a.y + b.y + c.y + d.y,
                a.z + b.z + c.z + d.z, a.w + b.w + c.w + d.w};
    ((float4*)sA)[tid] = s;
  }
  __syncthreads();  // B2

  // ---- matmul1: ddx = dx @ W1 (k-split, streamed reg W) ----
  mm_phase(sA, W1, sR[wv], k0, cgi, fb);
  __syncthreads();  // B3

  // ---- wave0: tp (t2 = dx + CG(dx, ddx)) ----
  if (wv == 0) {
    float dxv[12], ddx[12];
    {
      const float4* sa = (const float4*)(sA + lane * kCp);
      *(float4*)&dxv[0] = sa[0];
      *(float4*)&dxv[4] = sa[1];
      *(float4*)&dxv[8] = sa[2];
    }
    #pragma unroll
    for (int c = 0; c < 12; c++) {
      ddx[c] = sR[0][lane * kCp + c] + sR[1][lane * kCp + c] +
               sR[2][lane * kCp + c] + sR[3][lane * kCp + c];
    }
    float t2[12];
    #pragma unroll
    for (int c = 0; c < 9; c++) t2[c] = dxv[c];
    t2[9] = 0.f; t2[10] = 0.f; t2[11] = 0.f;
    #pragma unroll
    for (int q = 0; q < CG.n; q++) {
      t2[CG.c[q]] += CG.v[q] * dxv[CG.a[q]] * ddx[CG.b[q]];
    }
    float4* sa = (float4*)(sA + lane * kCp);
    sa[0] = *(float4*)&t2[0];
    sa[1] = *(float4*)&t2[4];
    sa[2] = *(float4*)&t2[8];
  }
  __syncthreads();  // B4

  // ---- matmul2: dx2 = t2 @ W2 (k-split, streamed reg W) ----
  mm_phase(sA, W2, sR[wv], k0, cgi, fb);
  __syncthreads();  // B5

  // ---- gate partials (k-split) ----
  {
    float g0 = 0.f, g1 = 0.f, g2 = 0.f;
    #pragma unroll 4
    for (int kk = 0; kk < 16; kk++) {
      int k = k0 + kk;
      float a = sR[0][k * kCp] + sR[1][k * kCp] + sR[2][k * kCp] + sR[3][k * kCp];
      g0 += a * Wg[k * 192 + lane];
      g1 += a * Wg[k * 192 + 64 + lane];
      g2 += a * Wg[k * 192 + 128 + lane];
    }
    sGp[wv][lane] = g0;
    sGp[wv][64 + lane] = g1;
    sGp[wv][128 + lane] = g2;
  }
  __syncthreads();  // B6

  // ---- wave0: dx3 = dx2 * sigmoid(gate)[lidx] -> sA ----
  if (wv == 0) {
    float dx2v[12];
    #pragma unroll
    for (int c = 0; c < 12; c++) {
      dx2v[c] = sR[0][lane * kCp + c] + sR[1][lane * kCp + c] +
                sR[2][lane * kCp + c] + sR[3][lane * kCp + c];
    }
    float g0 = bg[lane] + sGp[0][lane] + sGp[1][lane] + sGp[2][lane] + sGp[3][lane];
    float g1 = bg[64 + lane] + sGp[0][64 + lane] + sGp[1][64 + lane] +
               sGp[2][64 + lane] + sGp[3][64 + lane];
    float g2 = bg[128 + lane] + sGp[0][128 + lane] + sGp[1][128 + lane] +
               sGp[2][128 + lane] + sGp[3][128 + lane];
    g0 = 1.f / (1.f + expf(-g0));
    g1 = 1.f / (1.f + expf(-g1));
    g2 = 1.f / (1.f + expf(-g2));
    float dx3[12];
    dx3[0] = dx2v[0] * g0;
    dx3[1] = dx2v[1] * g1;
    dx3[2] = dx2v[2] * g1;
    dx3[3] = dx2v[3] * g1;
    #pragma unroll
    for (int c = 4; c < 9; c++) dx3[c] = dx2v[c] * g2;
    dx3[9] = 0.f; dx3[10] = 0.f; dx3[11] = 0.f;
    float4* sa = (float4*)(sA + lane * kCp);
    sa[0] = *(float4*)&dx3[0];
    sa[1] = *(float4*)&dx3[4];
    sa[2] = *(float4*)&dx3[8];
  }
  __syncthreads();  // B7

  // ---- matmul3: out = dx3 @ W3 (k-split, streamed reg W) ----
  mm_phase(sA, W3, sR[wv], k0, cgi, fb);
  __syncthreads();  // B8

  // ---- residual output ----
  if (T == 0) {
    // residual = x0 = emb[Z[atom]] in channel 0 only; out internal [f][12]
    if (tid < 192) {
      const int f = tid / 3, r = tid % 3;
      const float4* r0 = (const float4*)sR[0];
      const float4* r1 = (const float4*)sR[1];
      const float4* r2 = (const float4*)sR[2];
      const float4* r3 = (const float4*)sR[3];
      float4 a = r0[tid], b = r1[tid], c = r2[tid], d = r3[tid];
      float4 s = {a.x + b.x + c.x + d.x, a.y + b.y + c.y + d.y,
                  a.z + b.z + c.z + d.z, a.w + b.w + c.w + d.w};
      if (r == 0) s.x += emb[Z[atom] * kF + f];
      *(float4*)(x_out + atom * kXs + tid * 4) = s;
    }
  } else {
    // sum + residual (f-major, b128) -> sA, then c-major store
    if (tid < 192) {
      const float4* r0 = (const float4*)sR[0];
      const float4* r1 = (const float4*)sR[1];
      const float4* r2 = (const float4*)sR[2];
      const float4* r3 = (const float4*)sR[3];
      float4 a = r0[tid], b = r1[tid], c = r2[tid], d = r3[tid];
      float4 xi = *(const float4*)(x_in + atom * kXs + tid * 4);
      float4 s = {a.x + b.x + c.x + d.x + xi.x, a.y + b.y + c.y + d.y + xi.y,
                  a.z + b.z + c.z + d.z + xi.z, a.w + b.w + c.w + d.w + xi.w};
      ((float4*)sA)[tid] = s;
    }
    __syncthreads();  // B9
    #pragma unroll
    for (int r = 0; r < 3; r++) {
      int i = r * 256 + tid;        // 0..767, only < 576 valid
      if (i < kNsh * kF) {
        int c = i >> 6, f = i & 63;
        x_out[atom * (kNsh * kF) + i] = sA[f * kCp + c];
      }
    }
  }
}

// ---------------------------------------------------------------------------
// Launch: 3 dispatches (kernel boundaries provide all coherence)
// ---------------------------------------------------------------------------
extern "C" void kernel_launch(void* const* d_in, const int* in_sizes, int n_in,
                              void* d_out, int out_size, void* d_ws, size_t ws_size,
                              hipStream_t stream) {
  const int* Z        = (const int*)d_in[0];
  const float* rij    = (const float*)d_in[1];
  const int* idx_i    = (const int*)d_in[2];
  const int* idx_j    = (const int*)d_in[3];
  const float* emb    = (const float*)d_in[4];
  const float* Wf     = (const float*)d_in[5];
  const float* bf     = (const float*)d_in[6];
  const float* W1     = (const float*)d_in[7];
  const float* W2     = (const float*)d_in[8];
  const float* W3     = (const float*)d_in[9];
  const float* Wg     = (const float*)d_in[10];
  const float* bg     = (const float*)d_in[11];
  float* out = (float*)d_out;

  float* x1  = (float*)d_ws;                   // 768,000 floats
  float* pd  = x1 + kNAtoms * kXs;             // 320,000 floats (10000 x 32)
  float* pw  = pd + kNPairs * 32;              // 3,840,000 floats (2 x 10000 x 192)
  int*   seg = (int*)(pw + 2 * kNPairs * 192); // 1001 ints

  k_pre<<<kPreBlkTotal, 256, 0, stream>>>(rij, idx_i, Wf, bf, pd, pw, seg);

  // t = 0: emb-gather -> x1 (internal layout)
  k_inter<0><<<kNAtoms, 256, 0, stream>>>(
      pd, pw, seg, idx_j, Z, emb, x1,
      W1, W2, W3, Wg, bg, x1);

  // t = 1: x1-gather -> d_out (standard layout)
  k_inter<1><<<kNAtoms, 256, 0, stream>>>(
      pd, pw + kNPairs * 192, seg, idx_j, Z, emb, x1,
      W1 + kF * kF, W2 + kF * kF, W3 + kF * kF,
      Wg + kF * 192, bg + 192, out);
}

// Round 2
// 127.577 us; speedup vs baseline: 1.0948x; 1.0948x over previous
//
#include <hip/hip_runtime.h>
#include <cmath>

// ---------------------------------------------------------------------------
// Problem constants (from reference)
// ---------------------------------------------------------------------------
constexpr int kNsh    = 9;      // (LMAX+1)^2, LMAX=2
constexpr int kF      = 64;
constexpr int kNrbf   = 20;
constexpr int kNAtoms = 1000;
constexpr int kNPairs = 10000;
constexpr float kCutoffF = 5.0f;
constexpr int kMaxNZ  = 200;
constexpr int kCp     = 12;         // channel dim padded (9 -> 12) for b128
constexpr int kXs     = kF * kCp;   // 768 floats per atom, internal layout
constexpr int kWT     = 68;         // transposed filter row stride (pad 60->68)

// ---------------------------------------------------------------------------
// Compile-time real Clebsch-Gordan table (mirrors the reference _real_cg)
// ---------------------------------------------------------------------------
struct CGSparse {
  int n;
  int c[kMaxNZ];
  int a[kMaxNZ];
  int b[kMaxNZ];
  float v[kMaxNZ];
};

constexpr double cfact(int n) {
  double r = 1.0;
  for (int i = 2; i <= n; i++) r *= (double)i;
  return r;
}
constexpr double cabs_(double x) { return x < 0 ? -x : x; }
constexpr double csqrt_(double x) {
  if (x <= 0.0) return 0.0;
  double g = x < 1.0 ? 1.0 : x;
  for (int i = 0; i < 60; i++) g = 0.5 * (g + x / g);
  return g;
}

constexpr double cg_cplx(int l1, int m1, int l2, int m2, int l3, int m3) {
  if (m3 != m1 + m2) return 0.0;
  int lo = l1 > l2 ? l1 - l2 : l2 - l1;
  if (l3 < lo || l3 > l1 + l2) return 0.0;
  double pre = csqrt_((2 * l3 + 1) * cfact(l3 + l1 - l2) * cfact(l3 - l1 + l2) *
                      cfact(l1 + l2 - l3) / cfact(l1 + l2 + l3 + 1));
  pre *= csqrt_(cfact(l3 + m3) * cfact(l3 - m3) * cfact(l1 - m1) *
                cfact(l1 + m1) * cfact(l2 - m2) * cfact(l2 + m2));
  double s = 0.0;
  for (int k = 0; k <= l1 + l2 - l3; k++) {
    int d0 = k, d1 = l1 + l2 - l3 - k, d2 = l1 - m1 - k;
    int d3 = l2 + m2 - k, d4 = l3 - l2 + m1 + k, d5 = l3 - l1 - m2 + k;
    if (d0 < 0 || d1 < 0 || d2 < 0 || d3 < 0 || d4 < 0 || d5 < 0) continue;
    double den = cfact(d0) * cfact(d1) * cfact(d2) * cfact(d3) * cfact(d4) * cfact(d5);
    s += ((k % 2) ? -1.0 : 1.0) / den;
  }
  return pre * s;
}

constexpr CGSparse build_cg() {
  CGSparse out{};
  int lidx[9] = {0, 1, 1, 1, 2, 2, 2, 2, 2};
  int midx[9] = {0, -1, 0, 1, -2, -1, 0, 1, 2};
  double Ur[9][9] = {};
  double Ui[9][9] = {};
  for (int l = 0; l <= 2; l++) {
    int base = l * l + l;
    Ur[base][base] = 1.0;
    for (int m = 1; m <= l; m++) {
      double s2 = 1.0 / csqrt_(2.0);
      double sgn = (m % 2) ? -1.0 : 1.0;
      Ur[base + m][base - m] = s2;
      Ur[base + m][base + m] = sgn * s2;
      Ui[base - m][base - m] = s2;
      Ui[base - m][base + m] = -sgn * s2;
    }
  }
  double cgr[9][9][9] = {};
  for (int i = 0; i < 9; i++)
    for (int j = 0; j < 9; j++)
      for (int k = 0; k < 9; k++) {
        double cv = cg_cplx(lidx[i], midx[i], lidx[j], midx[j], lidx[k], midx[k]);
        if (cv == 0.0) continue;
        for (int a2 = 0; a2 < 9; a2++) {
          if (Ur[a2][i] == 0.0 && Ui[a2][i] == 0.0) continue;
          for (int b2 = 0; b2 < 9; b2++) {
            if (Ur[b2][j] == 0.0 && Ui[b2][j] == 0.0) continue;
            for (int c2 = 0; c2 < 9; c2++) {
              if (Ur[c2][k] == 0.0 && Ui[c2][k] == 0.0) continue;
              double ar = Ur[a2][i], ai = Ui[a2][i];
              double br = Ur[b2][j], bi = Ui[b2][j];
              double cr = Ur[c2][k], ci = -Ui[c2][k];  // conj
              double pr = ar * br - ai * bi;
              double pi = ar * bi + ai * br;
              double rr = pr * cr - pi * ci;  // real part
              cgr[c2][a2][b2] += rr * cv;
            }
          }
        }
      }
  int n = 0;
  for (int c2 = 0; c2 < 9; c2++)
    for (int a2 = 0; a2 < 9; a2++)
      for (int b2 = 0; b2 < 9; b2++) {
        bool mask = ((lidx[a2] + lidx[b2]) % 2) == (lidx[c2] % 2);
        double v = mask ? cgr[c2][a2][b2] : 0.0;
        if (cabs_(v) > 1e-9) {
          out.c[n] = c2;
          out.a[n] = a2;
          out.b[n] = b2;
          out.v[n] = (float)v;
          n++;
        }
      }
  out.n = n;
  return out;
}

constexpr CGSparse CG = build_cg();
static_assert(CG.n > 0 && CG.n <= kMaxNZ, "CG table size out of range");

// ---------------------------------------------------------------------------
// k_pre: compact per-pair record pd[32]: Y[0..8], cut[9], radial*cut[10..29]
// Repacked: 32 threads per pair (8 pairs/block) -> 1250 blocks, 94% lane use.
// | segment offsets (binary search, 4 blocks).
// ---------------------------------------------------------------------------
constexpr int kPreBlkPairs = kNPairs / 8;                 // 1250
constexpr int kPreBlkSeg   = (kNAtoms + 1 + 255) / 256;   // 4
constexpr int kPreBlkTotal = kPreBlkPairs + kPreBlkSeg;

__global__ __launch_bounds__(256) void k_pre(
    const float* __restrict__ rij, const int* __restrict__ idx_i,
    float* __restrict__ pd_all, int* __restrict__ seg) {
  const int blk = blockIdx.x;
  if (blk < kPreBlkPairs) {
    int sub = threadIdx.x >> 5;   // 0..7 pair within block
    int f = threadIdx.x & 31;     // slot 0..31 (30 used)
    int p = blk * 8 + sub;
    float rx = rij[3 * p + 0], ry = rij[3 * p + 1], rz = rij[3 * p + 2];
    float d = sqrtf(rx * rx + ry * ry + rz * rz);
    float inv = 1.0f / d;
    float x = rx * inv, y = ry * inv, z = rz * inv;
    const float c0 = 0.28209479177387814f;  // 0.5/sqrt(pi)
    const float c1 = 0.4886025119029199f;   // sqrt(3/(4pi))
    const float c2 = 1.0925484305920792f;   // 0.5*sqrt(15/pi)
    const float c3 = 0.31539156525252005f;  // 0.25*sqrt(5/pi)
    const float c4 = 0.5462742152960396f;   // 0.25*sqrt(15/pi)
    float cut = (d < kCutoffF) ? 0.5f * (cosf(d * (float)(M_PI / 5.0)) + 1.0f) : 0.0f;
    float val = 0.f;
    if (f < 9) {
      val =
          (f == 0) ? c0 :
          (f == 1) ? c1 * y :
          (f == 2) ? c1 * z :
          (f == 3) ? c1 * x :
          (f == 4) ? c2 * x * y :
          (f == 5) ? c2 * y * z :
          (f == 6) ? c3 * (3.0f * z * z - 1.0f) :
          (f == 7) ? c2 * x * z :
                     c4 * (x * x - y * y);
    } else if (f == 9) {
      val = cut;
    } else if (f < 30) {
      const float width = kCutoffF / (kNrbf - 1);
      const float coef = -0.5f / (width * width);
      float off = (kCutoffF * (f - 10)) / (kNrbf - 1);
      float tt = d - off;
      val = expf(coef * tt * tt) * cut;   // radial*cut (bias term uses cut)
    }
    if (f < 30) pd_all[p * 32 + f] = val;
  } else {
    int a = (blk - kPreBlkPairs) * 256 + threadIdx.x;
    if (a <= kNAtoms) {
      int lo = 0, hi = kNPairs;
      while (lo < hi) {
        int mid = (lo + hi) >> 1;
        if (idx_i[mid] < a) lo = mid + 1; else hi = mid;
      }
      seg[a] = lo;
    }
  }
}

// ---------------------------------------------------------------------------
// Helpers
// ---------------------------------------------------------------------------
// k-split matmul partial: wave covers 16 k-slices of the 12c x 64f tile.
// W streamed from global (L2-broadcast) in two 8-slice register stages.
__device__ __forceinline__ void mm_phase(const float* __restrict__ sIn,
                                         const float* __restrict__ W,
                                         float* __restrict__ sRw,
                                         int k0, int cgi, int fb) {
  if (cgi >= 3) return;
  const int c0 = cgi * 4;
  float acc[4][4];
  #pragma unroll
  for (int i = 0; i < 4; i++)
    #pragma unroll
    for (int j = 0; j < 4; j++) acc[i][j] = 0.f;
  #pragma unroll
  for (int half = 0; half < 2; half++) {
    float4 wr[8];
    #pragma unroll
    for (int kk = 0; kk < 8; kk++) {
      wr[kk] = *(const float4*)(W + (k0 + half * 8 + kk) * kF + fb);
    }
    #pragma unroll
    for (int kk = 0; kk < 8; kk++) {
      int k = k0 + half * 8 + kk;
      float4 av = *(const float4*)(sIn + k * kCp + c0);
      float4 wv = wr[kk];
      float a[4] = {av.x, av.y, av.z, av.w};
      float w[4] = {wv.x, wv.y, wv.z, wv.w};
      #pragma unroll
      for (int i = 0; i < 4; i++)
        #pragma unroll
        for (int j = 0; j < 4; j++) acc[i][j] += a[i] * w[j];
    }
  }
  #pragma unroll
  for (int j = 0; j < 4; j++) {
    float4 v = {acc[0][j], acc[1][j], acc[2][j], acc[3][j]};
    *(float4*)(sRw + (fb + j) * kCp + c0) = v;
  }
}

// ---------------------------------------------------------------------------
// k_inter<T>: fused message + update, one block (4 waves) per atom.
// Filters reconstructed per pair from a TRANSPOSED LDS copy of Wf:
//   sWfT[f][i], i = l*20+k, row stride 68 floats (pad for bank spread)
//   -> 15 ds_read_b128 per pair instead of 60 ds_read_b32.
// T==0: gather emb[Z[j]] (x0 virtual), write internal [f][12].
// T==1: gather x1, write standard [c][f] to out.
// ---------------------------------------------------------------------------
template <int T>
__global__ __launch_bounds__(256) void k_inter(
    const float* __restrict__ pd_all, const float* __restrict__ Wft,
    const float* __restrict__ bft, const int* __restrict__ seg,
    const int* __restrict__ idx_j, const int* __restrict__ Z,
    const float* __restrict__ emb, const float* __restrict__ x_in,
    const float* __restrict__ W1, const float* __restrict__ W2,
    const float* __restrict__ W3, const float* __restrict__ Wg,
    const float* __restrict__ bg, float* __restrict__ x_out) {
  const int atom = blockIdx.x;
  const int tid = threadIdx.x;
  const int wv = tid >> 6;          // wave 0..3
  const int lane = tid & 63;
  const int cgi = lane >> 4;        // 0..3 (3 idle in mm)
  const int fb = (lane & 15) * 4;
  const int k0 = wv * 16;           // k-range for this wave

  __shared__ __align__(16) float sWfT[kF * kWT];    // 17 KB transposed filters
  __shared__ __align__(16) float sA[kF * kCp];      // 3 KB staging, f-major
  __shared__ __align__(16) float sR[4][kF * kCp];   // 12 KB per-wave partials
  __shared__ __align__(16) float sGp[4][192];       // 3 KB gate partials

  // ---- stage Wf into LDS, transposing to per-lane-contiguous layout ----
  // source float4 i covers Wft floats m=4i..4i+3: m = k*192 + l*64 + f
  // (all 4 share k,l; f = m%64..+3). dest: sWfT[(f+q)*kWT + l*20+k].
  {
    const float4* g4 = (const float4*)Wft;
    #pragma unroll
    for (int rr = 0; rr < 4; rr++) {
      int i = rr * 256 + tid;
      if (i < kNrbf * 192 / 4) {
        float4 v = g4[i];
        int m = 4 * i;
        int k = m / 192, rem = m % 192;
        int l = rem / 64, f0 = rem % 64;
        int li = l * 20 + k;
        float va[4] = {v.x, v.y, v.z, v.w};
        #pragma unroll
        for (int q = 0; q < 4; q++) sWfT[(f0 + q) * kWT + li] = va[q];
      }
    }
  }
  const float bf0 = bft[lane], bf1 = bft[64 + lane], bf2 = bft[128 + lane];
  __syncthreads();  // B0

  // ---- message + aggregation (pairs split across 4 waves) ----
  {
    float y[12];
    #pragma unroll
    for (int c = 0; c < 12; c++) y[c] = 0.f;
    const int s0 = seg[atom], s1 = seg[atom + 1];
    const float* wrow = sWfT + lane * kWT;
    for (int p0 = s0 + wv; p0 < s1; p0 += 4) {
      const int p = __builtin_amdgcn_readfirstlane(p0);
      const int j = __builtin_amdgcn_readfirstlane(idx_j[p]);
      const float* pd = pd_all + p * 32;
      const float cut = pd[9];
      // reconstruct per-pair filters: Wl = bf*cut + sum_k (rad_k*cut)*Wf[k]
      float Wl[3] = {bf0 * cut, bf1 * cut, bf2 * cut};
      #pragma unroll
      for (int j4 = 0; j4 < 15; j4++) {
        float4 w = *(const float4*)(wrow + 4 * j4);
        float wa[4] = {w.x, w.y, w.z, w.w};
        #pragma unroll
        for (int q = 0; q < 4; q++) {
          constexpr int dummy = 0; (void)dummy;
          int i = 4 * j4 + q;          // compile-time under unroll
          Wl[i / 20] += pd[10 + (i % 20)] * wa[q];
        }
      }
      float YW[9];
      YW[0] = pd[0] * Wl[0];
      YW[1] = pd[1] * Wl[1];
      YW[2] = pd[2] * Wl[1];
      YW[3] = pd[3] * Wl[1];
      #pragma unroll
      for (int b = 4; b < 9; b++) YW[b] = pd[b] * Wl[2];
      if (T == 0) {
        // x[j] = emb[Z[j]] in channel 0 only: CG folds to a==0 entries
        float e = emb[Z[j] * kF + lane];
        #pragma unroll
        for (int q = 0; q < CG.n; q++) {
          if (CG.a[q] == 0) y[CG.c[q]] += CG.v[q] * YW[CG.b[q]] * e;
        }
      } else {
        const float* xj = x_in + j * kXs + lane * kCp;
        float xv[12];
        *(float4*)&xv[0] = *(const float4*)(xj + 0);
        *(float4*)&xv[4] = *(const float4*)(xj + 4);
        *(float4*)&xv[8] = *(const float4*)(xj + 8);
        #pragma unroll
        for (int q = 0; q < CG.n; q++) {
          y[CG.c[q]] += CG.v[q] * YW[CG.b[q]] * xv[CG.a[q]];
        }
      }
    }
    float4* r4 = (float4*)(sR[wv] + lane * kCp);
    r4[0] = *(float4*)&y[0];
    r4[1] = *(float4*)&y[4];
    r4[2] = *(float4*)&y[8];
  }
  __syncthreads();  // B1
  // reduce partials -> sA (dx, f-major); float4 granularity
  if (tid < 192) {
    const float4* r0 = (const float4*)sR[0];
    const float4* r1 = (const float4*)sR[1];
    const float4* r2 = (const float4*)sR[2];
    const float4* r3 = (const float4*)sR[3];
    float4 a = r0[tid], b = r1[tid], c = r2[tid], d = r3[tid];
    float4 s = {a.x + b.x + c.x + d.x, a.y + b.y + c.y + d.y,
                a.z + b.z + c.z + d.z, a.w + b.w + c.w + d.w};
    ((float4*)sA)[tid] = s;
  }
  __syncthreads();  // B2

  // ---- matmul1: ddx = dx @ W1 (k-split, streamed reg W) ----
  mm_phase(sA, W1, sR[wv], k0, cgi, fb);
  __syncthreads();  // B3

  // ---- wave0: tp (t2 = dx + CG(dx, ddx)) ----
  if (wv == 0) {
    float dxv[12], ddx[12];
    {
      const float4* sa = (const float4*)(sA + lane * kCp);
      *(float4*)&dxv[0] = sa[0];
      *(float4*)&dxv[4] = sa[1];
      *(float4*)&dxv[8] = sa[2];
    }
    #pragma unroll
    for (int c = 0; c < 12; c++) {
      ddx[c] = sR[0][lane * kCp + c] + sR[1][lane * kCp + c] +
               sR[2][lane * kCp + c] + sR[3][lane * kCp + c];
    }
    float t2[12];
    #pragma unroll
    for (int c = 0; c < 9; c++) t2[c] = dxv[c];
    t2[9] = 0.f; t2[10] = 0.f; t2[11] = 0.f;
    #pragma unroll
    for (int q = 0; q < CG.n; q++) {
      t2[CG.c[q]] += CG.v[q] * dxv[CG.a[q]] * ddx[CG.b[q]];
    }
    float4* sa = (float4*)(sA + lane * kCp);
    sa[0] = *(float4*)&t2[0];
    sa[1] = *(float4*)&t2[4];
    sa[2] = *(float4*)&t2[8];
  }
  __syncthreads();  // B4

  // ---- matmul2: dx2 = t2 @ W2 (k-split, streamed reg W) ----
  mm_phase(sA, W2, sR[wv], k0, cgi, fb);
  __syncthreads();  // B5

  // ---- gate partials (k-split) ----
  {
    float g0 = 0.f, g1 = 0.f, g2 = 0.f;
    #pragma unroll 4
    for (int kk = 0; kk < 16; kk++) {
      int k = k0 + kk;
      float a = sR[0][k * kCp] + sR[1][k * kCp] + sR[2][k * kCp] + sR[3][k * kCp];
      g0 += a * Wg[k * 192 + lane];
      g1 += a * Wg[k * 192 + 64 + lane];
      g2 += a * Wg[k * 192 + 128 + lane];
    }
    sGp[wv][lane] = g0;
    sGp[wv][64 + lane] = g1;
    sGp[wv][128 + lane] = g2;
  }
  __syncthreads();  // B6

  // ---- wave0: dx3 = dx2 * sigmoid(gate)[lidx] -> sA ----
  if (wv == 0) {
    float dx2v[12];
    #pragma unroll
    for (int c = 0; c < 12; c++) {
      dx2v[c] = sR[0][lane * kCp + c] + sR[1][lane * kCp + c] +
                sR[2][lane * kCp + c] + sR[3][lane * kCp + c];
    }
    float g0 = bg[lane] + sGp[0][lane] + sGp[1][lane] + sGp[2][lane] + sGp[3][lane];
    float g1 = bg[64 + lane] + sGp[0][64 + lane] + sGp[1][64 + lane] +
               sGp[2][64 + lane] + sGp[3][64 + lane];
    float g2 = bg[128 + lane] + sGp[0][128 + lane] + sGp[1][128 + lane] +
               sGp[2][128 + lane] + sGp[3][128 + lane];
    g0 = 1.f / (1.f + expf(-g0));
    g1 = 1.f / (1.f + expf(-g1));
    g2 = 1.f / (1.f + expf(-g2));
    float dx3[12];
    dx3[0] = dx2v[0] * g0;
    dx3[1] = dx2v[1] * g1;
    dx3[2] = dx2v[2] * g1;
    dx3[3] = dx2v[3] * g1;
    #pragma unroll
    for (int c = 4; c < 9; c++) dx3[c] = dx2v[c] * g2;
    dx3[9] = 0.f; dx3[10] = 0.f; dx3[11] = 0.f;
    float4* sa = (float4*)(sA + lane * kCp);
    sa[0] = *(float4*)&dx3[0];
    sa[1] = *(float4*)&dx3[4];
    sa[2] = *(float4*)&dx3[8];
  }
  __syncthreads();  // B7

  // ---- matmul3: out = dx3 @ W3 (k-split, streamed reg W) ----
  mm_phase(sA, W3, sR[wv], k0, cgi, fb);
  __syncthreads();  // B8

  // ---- residual output ----
  if (T == 0) {
    // residual = x0 = emb[Z[atom]] in channel 0 only; out internal [f][12]
    if (tid < 192) {
      const int f = tid / 3, r = tid % 3;
      const float4* r0 = (const float4*)sR[0];
      const float4* r1 = (const float4*)sR[1];
      const float4* r2 = (const float4*)sR[2];
      const float4* r3 = (const float4*)sR[3];
      float4 a = r0[tid], b = r1[tid], c = r2[tid], d = r3[tid];
      float4 s = {a.x + b.x + c.x + d.x, a.y + b.y + c.y + d.y,
                  a.z + b.z + c.z + d.z, a.w + b.w + c.w + d.w};
      if (r == 0) s.x += emb[Z[atom] * kF + f];
      *(float4*)(x_out + atom * kXs + tid * 4) = s;
    }
  } else {
    // sum + residual (f-major, b128) -> sA, then c-major store
    if (tid < 192) {
      const float4* r0 = (const float4*)sR[0];
      const float4* r1 = (const float4*)sR[1];
      const float4* r2 = (const float4*)sR[2];
      const float4* r3 = (const float4*)sR[3];
      float4 a = r0[tid], b = r1[tid], c = r2[tid], d = r3[tid];
      float4 xi = *(const float4*)(x_in + atom * kXs + tid * 4);
      float4 s = {a.x + b.x + c.x + d.x + xi.x, a.y + b.y + c.y + d.y + xi.y,
                  a.z + b.z + c.z + d.z + xi.z, a.w + b.w + c.w + d.w + xi.w};
      ((float4*)sA)[tid] = s;
    }
    __syncthreads();  // B9
    #pragma unroll
    for (int r = 0; r < 3; r++) {
      int i = r * 256 + tid;        // 0..767, only < 576 valid
      if (i < kNsh * kF) {
        int c = i >> 6, f = i & 63;
        x_out[atom * (kNsh * kF) + i] = sA[f * kCp + c];
      }
    }
  }
}

// ---------------------------------------------------------------------------
// Launch: 3 dispatches (kernel boundaries provide all coherence)
// ---------------------------------------------------------------------------
extern "C" void kernel_launch(void* const* d_in, const int* in_sizes, int n_in,
                              void* d_out, int out_size, void* d_ws, size_t ws_size,
                              hipStream_t stream) {
  const int* Z        = (const int*)d_in[0];
  const float* rij    = (const float*)d_in[1];
  const int* idx_i    = (const int*)d_in[2];
  const int* idx_j    = (const int*)d_in[3];
  const float* emb    = (const float*)d_in[4];
  const float* Wf     = (const float*)d_in[5];
  const float* bf     = (const float*)d_in[6];
  const float* W1     = (const float*)d_in[7];
  const float* W2     = (const float*)d_in[8];
  const float* W3     = (const float*)d_in[9];
  const float* Wg     = (const float*)d_in[10];
  const float* bg     = (const float*)d_in[11];
  float* out = (float*)d_out;

  float* x1  = (float*)d_ws;                   // 768,000 floats
  float* pd  = x1 + kNAtoms * kXs;             // 320,000 floats (10000 x 32)
  int*   seg = (int*)(pd + kNPairs * 32);      // 1001 ints

  k_pre<<<kPreBlkTotal, 256, 0, stream>>>(rij, idx_i, pd, seg);

  // t = 0: emb-gather -> x1 (internal layout)
  k_inter<0><<<kNAtoms, 256, 0, stream>>>(
      pd, Wf, bf, seg, idx_j, Z, emb, x1,
      W1, W2, W3, Wg, bg, x1);

  // t = 1: x1-gather -> d_out (standard layout)
  k_inter<1><<<kNAtoms, 256, 0, stream>>>(
      pd, Wf + kNrbf * 192, bf + 192, seg, idx_j, Z, emb, x1,
      W1 + kF * kF, W2 + kF * kF, W3 + kF * kF,
      Wg + kF * 192, bg + 192, out);
}

// Round 4
// 126.470 us; speedup vs baseline: 1.1044x; 1.0088x over previous
//
#include <hip/hip_runtime.h>
#include <cmath>

// ---------------------------------------------------------------------------
// Problem constants (from reference)
// ---------------------------------------------------------------------------
constexpr int kNsh    = 9;      // (LMAX+1)^2, LMAX=2
constexpr int kF      = 64;
constexpr int kNrbf   = 20;
constexpr int kNAtoms = 1000;
constexpr int kNPairs = 10000;
constexpr float kCutoffF = 5.0f;
constexpr int kMaxNZ  = 200;
constexpr int kCp     = 12;         // channel dim padded (9 -> 12) for b128
constexpr int kXs     = kF * kCp;   // 768 floats per atom, internal layout
constexpr int kWT     = 68;         // transposed filter row stride (pad 60->68)

// ---------------------------------------------------------------------------
// Compile-time real Clebsch-Gordan table (mirrors the reference _real_cg)
// ---------------------------------------------------------------------------
struct CGSparse {
  int n;
  int c[kMaxNZ];
  int a[kMaxNZ];
  int b[kMaxNZ];
  float v[kMaxNZ];
};

constexpr double cfact(int n) {
  double r = 1.0;
  for (int i = 2; i <= n; i++) r *= (double)i;
  return r;
}
constexpr double cabs_(double x) { return x < 0 ? -x : x; }
constexpr double csqrt_(double x) {
  if (x <= 0.0) return 0.0;
  double g = x < 1.0 ? 1.0 : x;
  for (int i = 0; i < 60; i++) g = 0.5 * (g + x / g);
  return g;
}

constexpr double cg_cplx(int l1, int m1, int l2, int m2, int l3, int m3) {
  if (m3 != m1 + m2) return 0.0;
  int lo = l1 > l2 ? l1 - l2 : l2 - l1;
  if (l3 < lo || l3 > l1 + l2) return 0.0;
  double pre = csqrt_((2 * l3 + 1) * cfact(l3 + l1 - l2) * cfact(l3 - l1 + l2) *
                      cfact(l1 + l2 - l3) / cfact(l1 + l2 + l3 + 1));
  pre *= csqrt_(cfact(l3 + m3) * cfact(l3 - m3) * cfact(l1 - m1) *
                cfact(l1 + m1) * cfact(l2 - m2) * cfact(l2 + m2));
  double s = 0.0;
  for (int k = 0; k <= l1 + l2 - l3; k++) {
    int d0 = k, d1 = l1 + l2 - l3 - k, d2 = l1 - m1 - k;
    int d3 = l2 + m2 - k, d4 = l3 - l2 + m1 + k, d5 = l3 - l1 - m2 + k;
    if (d0 < 0 || d1 < 0 || d2 < 0 || d3 < 0 || d4 < 0 || d5 < 0) continue;
    double den = cfact(d0) * cfact(d1) * cfact(d2) * cfact(d3) * cfact(d4) * cfact(d5);
    s += ((k % 2) ? -1.0 : 1.0) / den;
  }
  return pre * s;
}

constexpr CGSparse build_cg() {
  CGSparse out{};
  int lidx[9] = {0, 1, 1, 1, 2, 2, 2, 2, 2};
  int midx[9] = {0, -1, 0, 1, -2, -1, 0, 1, 2};
  double Ur[9][9] = {};
  double Ui[9][9] = {};
  for (int l = 0; l <= 2; l++) {
    int base = l * l + l;
    Ur[base][base] = 1.0;
    for (int m = 1; m <= l; m++) {
      double s2 = 1.0 / csqrt_(2.0);
      double sgn = (m % 2) ? -1.0 : 1.0;
      Ur[base + m][base - m] = s2;
      Ur[base + m][base + m] = sgn * s2;
      Ui[base - m][base - m] = s2;
      Ui[base - m][base + m] = -sgn * s2;
    }
  }
  double cgr[9][9][9] = {};
  for (int i = 0; i < 9; i++)
    for (int j = 0; j < 9; j++)
      for (int k = 0; k < 9; k++) {
        double cv = cg_cplx(lidx[i], midx[i], lidx[j], midx[j], lidx[k], midx[k]);
        if (cv == 0.0) continue;
        for (int a2 = 0; a2 < 9; a2++) {
          if (Ur[a2][i] == 0.0 && Ui[a2][i] == 0.0) continue;
          for (int b2 = 0; b2 < 9; b2++) {
            if (Ur[b2][j] == 0.0 && Ui[b2][j] == 0.0) continue;
            for (int c2 = 0; c2 < 9; c2++) {
              if (Ur[c2][k] == 0.0 && Ui[c2][k] == 0.0) continue;
              double ar = Ur[a2][i], ai = Ui[a2][i];
              double br = Ur[b2][j], bi = Ui[b2][j];
              double cr = Ur[c2][k], ci = -Ui[c2][k];  // conj
              double pr = ar * br - ai * bi;
              double pi = ar * bi + ai * br;
              double rr = pr * cr - pi * ci;  // real part
              cgr[c2][a2][b2] += rr * cv;
            }
          }
        }
      }
  int n = 0;
  for (int c2 = 0; c2 < 9; c2++)
    for (int a2 = 0; a2 < 9; a2++)
      for (int b2 = 0; b2 < 9; b2++) {
        bool mask = ((lidx[a2] + lidx[b2]) % 2) == (lidx[c2] % 2);
        double v = mask ? cgr[c2][a2][b2] : 0.0;
        if (cabs_(v) > 1e-9) {
          out.c[n] = c2;
          out.a[n] = a2;
          out.b[n] = b2;
          out.v[n] = (float)v;
          n++;
        }
      }
  out.n = n;
  return out;
}

constexpr CGSparse CG = build_cg();
static_assert(CG.n > 0 && CG.n <= kMaxNZ, "CG table size out of range");

// ---------------------------------------------------------------------------
// Wf staging: transpose to per-lane-contiguous layout in LDS.
// sWfT[f][i], i = l*20+k, row stride kWT floats.
// ---------------------------------------------------------------------------
__device__ __forceinline__ void stage_wft(const float* __restrict__ Wft,
                                          float* __restrict__ sWfT, int tid) {
  const float4* g4 = (const float4*)Wft;
  #pragma unroll
  for (int rr = 0; rr < 4; rr++) {
    int i = rr * 256 + tid;
    if (i < kNrbf * 192 / 4) {
      float4 v = g4[i];
      int m = 4 * i;
      int k = m / 192, rem = m % 192;
      int l = rem / 64, f0 = rem % 64;
      int li = l * 20 + k;
      float va[4] = {v.x, v.y, v.z, v.w};
      #pragma unroll
      for (int q = 0; q < 4; q++) sWfT[(f0 + q) * kWT + li] = va[q];
    }
  }
}

// k-split matmul partial: wave covers 16 k-slices of the 12c x 64f tile.
// W streamed from global (L2-broadcast) in two 8-slice register stages.
__device__ __forceinline__ void mm_phase(const float* __restrict__ sIn,
                                         const float* __restrict__ W,
                                         float* __restrict__ sRw,
                                         int k0, int cgi, int fb) {
  if (cgi >= 3) return;
  const int c0 = cgi * 4;
  float acc[4][4];
  #pragma unroll
  for (int i = 0; i < 4; i++)
    #pragma unroll
    for (int j = 0; j < 4; j++) acc[i][j] = 0.f;
  #pragma unroll
  for (int half = 0; half < 2; half++) {
    float4 wr[8];
    #pragma unroll
    for (int kk = 0; kk < 8; kk++) {
      wr[kk] = *(const float4*)(W + (k0 + half * 8 + kk) * kF + fb);
    }
    #pragma unroll
    for (int kk = 0; kk < 8; kk++) {
      int k = k0 + half * 8 + kk;
      float4 av = *(const float4*)(sIn + k * kCp + c0);
      float4 wv = wr[kk];
      float a[4] = {av.x, av.y, av.z, av.w};
      float w[4] = {wv.x, wv.y, wv.z, wv.w};
      #pragma unroll
      for (int i = 0; i < 4; i++)
        #pragma unroll
        for (int j = 0; j < 4; j++) acc[i][j] += a[i] * w[j];
    }
  }
  #pragma unroll
  for (int j = 0; j < 4; j++) {
    float4 v = {acc[0][j], acc[1][j], acc[2][j], acc[3][j]};
    *(float4*)(sRw + (fb + j) * kCp + c0) = v;
  }
}

// ---------------------------------------------------------------------------
// interaction<T>: one block (4 waves) per atom; sWfT staged, s0/s1 known.
// T==0: gather emb[Z[j]] (x0 virtual), write internal [f][12] to x_out.
// T==1: gather x_in, write standard [c][f] to x_out.
// ---------------------------------------------------------------------------
template <int T>
__device__ __forceinline__ void interaction(
    const float* __restrict__ sWfT, float* __restrict__ sA,
    float (*__restrict__ sR)[kF * kCp], float (*__restrict__ sGp)[192],
    const float* __restrict__ pd_all, const float* __restrict__ bft,
    int s0, int s1, const int* __restrict__ idx_j,
    const int* __restrict__ Z, const float* __restrict__ emb,
    const float* __restrict__ x_in,
    const float* __restrict__ W1, const float* __restrict__ W2,
    const float* __restrict__ W3, const float* __restrict__ Wg,
    const float* __restrict__ bg, float* __restrict__ x_out) {
  const int atom = blockIdx.x;
  const int tid = threadIdx.x;
  const int wv = tid >> 6;          // wave 0..3
  const int lane = tid & 63;
  const int cgi = lane >> 4;        // 0..3 (3 idle in mm)
  const int fb = (lane & 15) * 4;
  const int k0 = wv * 16;           // k-range for this wave

  const float bf0 = bft[lane], bf1 = bft[64 + lane], bf2 = bft[128 + lane];

  // ---- message + aggregation (pairs split across 4 waves) ----
  {
    float y[12];
    #pragma unroll
    for (int c = 0; c < 12; c++) y[c] = 0.f;
    const float* wrow = sWfT + lane * kWT;
    for (int p0 = s0 + wv; p0 < s1; p0 += 4) {
      const int p = __builtin_amdgcn_readfirstlane(p0);
      const int j = __builtin_amdgcn_readfirstlane(idx_j[p]);
      const float* pd = pd_all + p * 32;
      const float cut = pd[9];
      // reconstruct per-pair filters: Wl = bf*cut + sum_k (rad_k*cut)*Wf[k]
      float Wl[3] = {bf0 * cut, bf1 * cut, bf2 * cut};
      #pragma unroll
      for (int j4 = 0; j4 < 15; j4++) {
        float4 w = *(const float4*)(wrow + 4 * j4);
        float wa[4] = {w.x, w.y, w.z, w.w};
        #pragma unroll
        for (int q = 0; q < 4; q++) {
          int i = 4 * j4 + q;          // compile-time under unroll
          Wl[i / 20] += pd[10 + (i % 20)] * wa[q];
        }
      }
      float YW[9];
      YW[0] = pd[0] * Wl[0];
      YW[1] = pd[1] * Wl[1];
      YW[2] = pd[2] * Wl[1];
      YW[3] = pd[3] * Wl[1];
      #pragma unroll
      for (int b = 4; b < 9; b++) YW[b] = pd[b] * Wl[2];
      if (T == 0) {
        // x[j] = emb[Z[j]] in channel 0 only: CG folds to a==0 entries
        float e = emb[Z[j] * kF + lane];
        #pragma unroll
        for (int q = 0; q < CG.n; q++) {
          if (CG.a[q] == 0) y[CG.c[q]] += CG.v[q] * YW[CG.b[q]] * e;
        }
      } else {
        const float* xj = x_in + j * kXs + lane * kCp;
        float xv[12];
        *(float4*)&xv[0] = *(const float4*)(xj + 0);
        *(float4*)&xv[4] = *(const float4*)(xj + 4);
        *(float4*)&xv[8] = *(const float4*)(xj + 8);
        #pragma unroll
        for (int q = 0; q < CG.n; q++) {
          y[CG.c[q]] += CG.v[q] * YW[CG.b[q]] * xv[CG.a[q]];
        }
      }
    }
    float4* r4 = (float4*)(sR[wv] + lane * kCp);
    r4[0] = *(float4*)&y[0];
    r4[1] = *(float4*)&y[4];
    r4[2] = *(float4*)&y[8];
  }
  __syncthreads();  // B1
  // reduce partials -> sA (dx, f-major); float4 granularity
  if (tid < 192) {
    const float4* r0 = (const float4*)sR[0];
    const float4* r1 = (const float4*)sR[1];
    const float4* r2 = (const float4*)sR[2];
    const float4* r3 = (const float4*)sR[3];
    float4 a = r0[tid], b = r1[tid], c = r2[tid], d = r3[tid];
    float4 s = {a.x + b.x + c.x + d.x, a.y + b.y + c.y + d.y,
                a.z + b.z + c.z + d.z, a.w + b.w + c.w + d.w};
    ((float4*)sA)[tid] = s;
  }
  __syncthreads();  // B2

  // ---- matmul1: ddx = dx @ W1 (k-split, streamed reg W) ----
  mm_phase(sA, W1, sR[wv], k0, cgi, fb);
  __syncthreads();  // B3

  // ---- wave0: tp (t2 = dx + CG(dx, ddx)) ----
  if (wv == 0) {
    float dxv[12], ddx[12];
    {
      const float4* sa = (const float4*)(sA + lane * kCp);
      *(float4*)&dxv[0] = sa[0];
      *(float4*)&dxv[4] = sa[1];
      *(float4*)&dxv[8] = sa[2];
    }
    #pragma unroll
    for (int c = 0; c < 12; c++) {
      ddx[c] = sR[0][lane * kCp + c] + sR[1][lane * kCp + c] +
               sR[2][lane * kCp + c] + sR[3][lane * kCp + c];
    }
    float t2[12];
    #pragma unroll
    for (int c = 0; c < 9; c++) t2[c] = dxv[c];
    t2[9] = 0.f; t2[10] = 0.f; t2[11] = 0.f;
    #pragma unroll
    for (int q = 0; q < CG.n; q++) {
      t2[CG.c[q]] += CG.v[q] * dxv[CG.a[q]] * ddx[CG.b[q]];
    }
    float4* sa = (float4*)(sA + lane * kCp);
    sa[0] = *(float4*)&t2[0];
    sa[1] = *(float4*)&t2[4];
    sa[2] = *(float4*)&t2[8];
  }
  __syncthreads();  // B4

  // ---- matmul2: dx2 = t2 @ W2 (k-split, streamed reg W) ----
  mm_phase(sA, W2, sR[wv], k0, cgi, fb);
  __syncthreads();  // B5

  // ---- gate partials (k-split) ----
  {
    float g0 = 0.f, g1 = 0.f, g2 = 0.f;
    #pragma unroll 4
    for (int kk = 0; kk < 16; kk++) {
      int k = k0 + kk;
      float a = sR[0][k * kCp] + sR[1][k * kCp] + sR[2][k * kCp] + sR[3][k * kCp];
      g0 += a * Wg[k * 192 + lane];
      g1 += a * Wg[k * 192 + 64 + lane];
      g2 += a * Wg[k * 192 + 128 + lane];
    }
    sGp[wv][lane] = g0;
    sGp[wv][64 + lane] = g1;
    sGp[wv][128 + lane] = g2;
  }
  __syncthreads();  // B6

  // ---- wave0: dx3 = dx2 * sigmoid(gate)[lidx] -> sA ----
  if (wv == 0) {
    float dx2v[12];
    #pragma unroll
    for (int c = 0; c < 12; c++) {
      dx2v[c] = sR[0][lane * kCp + c] + sR[1][lane * kCp + c] +
                sR[2][lane * kCp + c] + sR[3][lane * kCp + c];
    }
    float g0 = bg[lane] + sGp[0][lane] + sGp[1][lane] + sGp[2][lane] + sGp[3][lane];
    float g1 = bg[64 + lane] + sGp[0][64 + lane] + sGp[1][64 + lane] +
               sGp[2][64 + lane] + sGp[3][64 + lane];
    float g2 = bg[128 + lane] + sGp[0][128 + lane] + sGp[1][128 + lane] +
               sGp[2][128 + lane] + sGp[3][128 + lane];
    g0 = 1.f / (1.f + expf(-g0));
    g1 = 1.f / (1.f + expf(-g1));
    g2 = 1.f / (1.f + expf(-g2));
    float dx3[12];
    dx3[0] = dx2v[0] * g0;
    dx3[1] = dx2v[1] * g1;
    dx3[2] = dx2v[2] * g1;
    dx3[3] = dx2v[3] * g1;
    #pragma unroll
    for (int c = 4; c < 9; c++) dx3[c] = dx2v[c] * g2;
    dx3[9] = 0.f; dx3[10] = 0.f; dx3[11] = 0.f;
    float4* sa = (float4*)(sA + lane * kCp);
    sa[0] = *(float4*)&dx3[0];
    sa[1] = *(float4*)&dx3[4];
    sa[2] = *(float4*)&dx3[8];
  }
  __syncthreads();  // B7

  // ---- matmul3: out = dx3 @ W3 (k-split, streamed reg W) ----
  mm_phase(sA, W3, sR[wv], k0, cgi, fb);
  __syncthreads();  // B8

  // ---- residual output ----
  if (T == 0) {
    // residual = x0 = emb[Z[atom]] in channel 0 only; out internal [f][12]
    if (tid < 192) {
      const int f = tid / 3, r = tid % 3;
      const float4* r0 = (const float4*)sR[0];
      const float4* r1 = (const float4*)sR[1];
      const float4* r2 = (const float4*)sR[2];
      const float4* r3 = (const float4*)sR[3];
      float4 a = r0[tid], b = r1[tid], c = r2[tid], d = r3[tid];
      float4 s = {a.x + b.x + c.x + d.x, a.y + b.y + c.y + d.y,
                  a.z + b.z + c.z + d.z, a.w + b.w + c.w + d.w};
      if (r == 0) s.x += emb[Z[atom] * kF + f];
      *(float4*)(x_out + atom * kXs + tid * 4) = s;
    }
  } else {
    // sum + residual (f-major, b128) -> sA, then c-major store
    if (tid < 192) {
      const float4* r0 = (const float4*)sR[0];
      const float4* r1 = (const float4*)sR[1];
      const float4* r2 = (const float4*)sR[2];
      const float4* r3 = (const float4*)sR[3];
      float4 a = r0[tid], b = r1[tid], c = r2[tid], d = r3[tid];
      float4 xi = *(const float4*)(x_in + atom * kXs + tid * 4);
      float4 s = {a.x + b.x + c.x + d.x + xi.x, a.y + b.y + c.y + d.y + xi.y,
                  a.z + b.z + c.z + d.z + xi.z, a.w + b.w + c.w + d.w + xi.w};
      ((float4*)sA)[tid] = s;
    }
    __syncthreads();  // B9
    #pragma unroll
    for (int r = 0; r < 3; r++) {
      int i = r * 256 + tid;        // 0..767, only < 576 valid
      if (i < kNsh * kF) {
        int c = i >> 6, f = i & 63;
        x_out[atom * (kNsh * kF) + i] = sA[f * kCp + c];
      }
    }
  }
}

// ---------------------------------------------------------------------------
// k_inter<T>: T==0 folds seg-bsearch + pd precompute into its prologue
// (pairs [seg[atom],seg[atom+1]) are owned exclusively by this block, and
// seg derives from input idx_i alone -> no cross-block dependency).
// pd is also written to global for T==1's reuse (kernel-boundary coherence);
// seg[atom] stashed likewise (duplicate identical writes are benign).
// ---------------------------------------------------------------------------
template <int T>
__global__ __launch_bounds__(256) void k_inter(
    const float* __restrict__ rij, const int* __restrict__ idx_i,
    const int* __restrict__ idx_j, const int* __restrict__ Z,
    const float* __restrict__ emb, const float* __restrict__ Wft,
    const float* __restrict__ bft, const float* __restrict__ W1,
    const float* __restrict__ W2, const float* __restrict__ W3,
    const float* __restrict__ Wg, const float* __restrict__ bg,
    const float* __restrict__ x_in, float* __restrict__ pd_all,
    int* __restrict__ seg, float* __restrict__ x_out) {
  const int atom = blockIdx.x;
  const int tid = threadIdx.x;

  __shared__ __align__(16) float sWfT[kF * kWT];    // 17 KB transposed filters
  __shared__ __align__(16) float sA[kF * kCp];      // 3 KB staging, f-major
  __shared__ __align__(16) float sR[4][kF * kCp];   // 12 KB per-wave partials
  __shared__ __align__(16) float sGp[4][192];       // 3 KB gate partials
  __shared__ int sSeg[2];

  stage_wft(Wft, sWfT, tid);

  int s0, s1;
  if (T == 0) {
    // ---- seg: lanes 0,1 of wave 0 do the two binary searches ----
    if (tid < 2) {
      const int a = atom + tid;
      int lo = 0, hi = kNPairs;
      while (lo < hi) {
        int mid = (lo + hi) >> 1;
        if (idx_i[mid] < a) lo = mid + 1; else hi = mid;
      }
      sSeg[tid] = lo;
      seg[a] = lo;   // block b writes seg[b], seg[b+1]; overlaps identical
    }
    __syncthreads();  // Ba: sSeg + sWfT visible
    s0 = sSeg[0];
    s1 = sSeg[1];
    // ---- pd for own pairs: 8 pair-slots x 32 threads ----
    {
      const int sub = tid >> 5;     // 0..7
      const int f = tid & 31;       // slot 0..31 (30 used)
      const int npair = s1 - s0;
      for (int pp = sub; pp < npair; pp += 8) {
        const int p = s0 + pp;
        float rx = rij[3 * p + 0], ry = rij[3 * p + 1], rz = rij[3 * p + 2];
        float d = sqrtf(rx * rx + ry * ry + rz * rz);
        float inv = 1.0f / d;
        float x = rx * inv, y = ry * inv, z = rz * inv;
        const float c0 = 0.28209479177387814f;  // 0.5/sqrt(pi)
        const float c1 = 0.4886025119029199f;   // sqrt(3/(4pi))
        const float c2 = 1.0925484305920792f;   // 0.5*sqrt(15/pi)
        const float c3 = 0.31539156525252005f;  // 0.25*sqrt(5/pi)
        const float c4 = 0.5462742152960396f;   // 0.25*sqrt(15/pi)
        float cut = (d < kCutoffF) ? 0.5f * (cosf(d * (float)(M_PI / 5.0)) + 1.0f) : 0.0f;
        float val = 0.f;
        if (f < 9) {
          val =
              (f == 0) ? c0 :
              (f == 1) ? c1 * y :
              (f == 2) ? c1 * z :
              (f == 3) ? c1 * x :
              (f == 4) ? c2 * x * y :
              (f == 5) ? c2 * y * z :
              (f == 6) ? c3 * (3.0f * z * z - 1.0f) :
              (f == 7) ? c2 * x * z :
                         c4 * (x * x - y * y);
        } else if (f == 9) {
          val = cut;
        } else if (f < 30) {
          const float width = kCutoffF / (kNrbf - 1);
          const float coef = -0.5f / (width * width);
          float off = (kCutoffF * (f - 10)) / (kNrbf - 1);
          float tt = d - off;
          val = expf(coef * tt * tt) * cut;   // radial*cut (bias uses cut)
        }
        if (f < 30) pd_all[p * 32 + f] = val;
      }
    }
    __syncthreads();  // Bb: pd writes drained (vmcnt) -> L2-visible to block
  } else {
    s0 = seg[atom];
    s1 = seg[atom + 1];
    __syncthreads();  // B0: sWfT visible
  }

  interaction<T>(sWfT, sA, sR, sGp, pd_all, bft, s0, s1, idx_j, Z, emb,
                 x_in, W1, W2, W3, Wg, bg, x_out);
}

// ---------------------------------------------------------------------------
// Launch: 2 dispatches (kernel boundary provides t0 -> t1 coherence)
// ---------------------------------------------------------------------------
extern "C" void kernel_launch(void* const* d_in, const int* in_sizes, int n_in,
                              void* d_out, int out_size, void* d_ws, size_t ws_size,
                              hipStream_t stream) {
  const int* Z        = (const int*)d_in[0];
  const float* rij    = (const float*)d_in[1];
  const int* idx_i    = (const int*)d_in[2];
  const int* idx_j    = (const int*)d_in[3];
  const float* emb    = (const float*)d_in[4];
  const float* Wf     = (const float*)d_in[5];
  const float* bf     = (const float*)d_in[6];
  const float* W1     = (const float*)d_in[7];
  const float* W2     = (const float*)d_in[8];
  const float* W3     = (const float*)d_in[9];
  const float* Wg     = (const float*)d_in[10];
  const float* bg     = (const float*)d_in[11];
  float* out = (float*)d_out;

  float* x1  = (float*)d_ws;                   // 768,000 floats
  float* pd  = x1 + kNAtoms * kXs;             // 320,000 floats (10000 x 32)
  int*   seg = (int*)(pd + kNPairs * 32);      // 1001 ints

  // t = 0: seg + pd in prologue, emb-gather -> x1 (internal layout)
  k_inter<0><<<kNAtoms, 256, 0, stream>>>(
      rij, idx_i, idx_j, Z, emb, Wf, bf,
      W1, W2, W3, Wg, bg,
      (const float*)nullptr, pd, seg, x1);

  // t = 1: x1-gather -> d_out (standard layout)
  k_inter<1><<<kNAtoms, 256, 0, stream>>>(
      rij, idx_i, idx_j, Z, emb, Wf + kNrbf * 192, bf + 192,
      W1 + kF * kF, W2 + kF * kF, W3 + kF * kF,
      Wg + kF * 192, bg + 192,
      x1, pd, seg, out);
}